// Round 4
// baseline (401.280 us; speedup 1.0000x reference)
//
#include <hip/hip_runtime.h>
#include <hip/hip_bf16.h>
#include <float.h>

typedef _Float16 f16;
typedef __attribute__((ext_vector_type(8))) _Float16 half8;
typedef __attribute__((ext_vector_type(4))) float floatx4;
typedef unsigned short u16;
typedef unsigned int u32;

// Problem constants
#define DIM   128
#define HW    4096
#define NPOS  131072
#define K     512
#define ZSTRIDE_B 524288

// Output layout (floats)
#define Q_OFF     0
#define LOSS_OFF  16777216
#define IDX_OFF   16777217
#define NEMB_OFF  16908289
#define NCS_OFF   16973825
#define NEA_OFF   16974337

// ---------------------------------------------------------------------------
// k_prep: split codebook into f16 hi/lo, written in the (nc,dc)-TILED layout
// k_assign stages from: tile t=(nc*4+dc) holds 256 codes x 32 dims, row-major.
__global__ __launch_bounds__(256) void k_prep(const float* __restrict__ emb,
                                              u16* __restrict__ ehi,
                                              u16* __restrict__ elo) {
    int lin = blockIdx.x * 256 + threadIdx.x;   // 65536
    int d = lin >> 9, k = lin & 511;
    float v = emb[lin];                          // coalesced
    f16 h = (f16)v;
    f16 l = (f16)(v - (float)h);
    int tile = ((k >> 8) << 2) + (d >> 5);       // nc*4 + dc
    int idx = (tile << 13) + ((k & 255) << 5) + (d & 31);
    union { f16 f; u16 u; } uh, ul; uh.f = h; ul.f = l;
    ehi[idx] = uh.u;
    elo[idx] = ul.u;
}

// ---------------------------------------------------------------------------
__global__ __launch_bounds__(512) void k_e2(const float* __restrict__ emb,
                                            float* __restrict__ e2) {
    int k = threadIdx.x;
    float s = 0.f;
    #pragma unroll 8
    for (int d = 0; d < DIM; ++d) {
        float v = emb[d * K + k];
        s = fmaf(v, v, s);
    }
    e2[k] = s;
}

// ---------------------------------------------------------------------------
// k_assign v2: 64 pos/block, 512 codes, D=128. 3-pass f16-split MFMA.
// Per-wave private es staging (no barriers in K-loop), double-buffered
// register prefetch, XOR-swizzled xs (no pad), 53248 B LDS -> 3 blocks/CU.
__global__ __launch_bounds__(256, 3) void k_assign(const float* __restrict__ z,
                                                   const float* __restrict__ emb,
                                                   const uint4* __restrict__ gh4,
                                                   const uint4* __restrict__ gl4,
                                                   const float* __restrict__ e2,
                                                   float* __restrict__ out,
                                                   float* __restrict__ lossAcc) {
    __shared__ __align__(16) char smem[53248];
    f16* xs_h = (f16*)smem;                 // 64 pos x 128 d, swizzled (16384 B)
    f16* xs_l = (f16*)(smem + 16384);       // 16384 B
    f16* es_h = (f16*)(smem + 32768);       // 4 waves x 32 rows x 40 f16 (10240 B)
    f16* es_l = (f16*)(smem + 43008);       // 10240 B

    const int tid  = threadIdx.x;
    const int lane = tid & 63;
    const int wv   = tid >> 6;
    const int n0   = blockIdx.x * 64;
    const int b    = n0 >> 12;
    const int hw0  = n0 & 4095;
    const float* zb = z + b * ZSTRIDE_B + hw0;
    const int l15  = lane & 15;
    const int quad = lane >> 4;

    // ---- stage X split (64 pos x 128 d), XOR-swizzled chunk layout
    #pragma unroll
    for (int it = 0; it < 16; ++it) {
        int lin = tid + it * 256;
        int i  = lin & 63;          // position (lanes consecutive -> coalesced)
        int dp = lin >> 6;          // d-pair 0..63
        float v0 = zb[(2 * dp) * HW + i];
        float v1 = zb[(2 * dp + 1) * HW + i];
        f16 h0 = (f16)v0; f16 l0 = (f16)(v0 - (float)h0);
        f16 h1 = (f16)v1; f16 l1 = (f16)(v1 - (float)h1);
        int cc = (dp >> 2) ^ (i & 7);          // swizzled 16B-chunk index
        int off = i * 64 + cc * 4 + (dp & 3);  // u32 offset
        union { f16 f[2]; u32 u; } ph, pl;
        ph.f[0] = h0; ph.f[1] = h1;
        pl.f[0] = l0; pl.f[1] = l1;
        ((u32*)xs_h)[off] = ph.u;
        ((u32*)xs_l)[off] = pl.u;
    }
    __syncthreads();

    float bestD[4][4];
    int   bestI[4][4];
    #pragma unroll
    for (int t = 0; t < 4; ++t)
        #pragma unroll
        for (int r = 0; r < 4; ++r) { bestD[t][r] = FLT_MAX; bestI[t][r] = 0x7fffffff; }

    floatx4 acc[4][4];
    #pragma unroll
    for (int t = 0; t < 4; ++t)
        #pragma unroll
        for (int g = 0; g < 4; ++g) acc[t][g] = (floatx4){0.f, 0.f, 0.f, 0.f};

    f16* esw_h = es_h + wv * 1280;   // 32 rows x 40 f16
    f16* esw_l = es_l + wv * 1280;
    half8 ah[4], al[4];
    uint4 rhA[2], rlA[2], rhB[2], rlB[2];

    // preload it=0 (nc0,dc0,sub0)
    {
        int nb = wv * 256;
        rhA[0] = gh4[nb + lane]; rhA[1] = gh4[nb + 64 + lane];
        rlA[0] = gl4[nb + lane]; rlA[1] = gl4[nb + 64 + lane];
    }

    for (int it2 = 0; it2 < 8; ++it2) {
        const int nc = it2 >> 2, dc = it2 & 3;
        const int tbase = (nc * 4 + dc) * 1024 + wv * 256;
        // prefetch sub1 of this tile
        {
            int nb = tbase + 128;
            rhB[0] = gh4[nb + lane]; rhB[1] = gh4[nb + 64 + lane];
            rlB[0] = gl4[nb + lane]; rlB[1] = gl4[nb + 64 + lane];
        }
        // write sub0 es (wave-private; in-order DS makes this safe)
        #pragma unroll
        for (int q = 0; q < 2; ++q) {
            int a = (q * 16 + (lane >> 2)) * 40 + (lane & 3) * 8;
            *(uint4*)&esw_h[a] = rhA[q];
            *(uint4*)&esw_l[a] = rlA[q];
        }
        // A fragments for this dc (shared by both subs)
        #pragma unroll
        for (int t = 0; t < 4; ++t) {
            int i = t * 16 + l15;
            int cc = (dc * 4 + quad) ^ (i & 7);
            ah[t] = ((const half8*)xs_h)[i * 16 + cc];
            al[t] = ((const half8*)xs_l)[i * 16 + cc];
        }
        // ---- sub 0 MFMAs
        #pragma unroll
        for (int nt = 0; nt < 2; ++nt) {
            int a = (nt * 16 + l15) * 40 + quad * 8;
            half8 bh = *(const half8*)&esw_h[a];
            half8 bl = *(const half8*)&esw_l[a];
            #pragma unroll
            for (int t = 0; t < 4; ++t) {
                acc[t][nt] = __builtin_amdgcn_mfma_f32_16x16x32_f16(ah[t], bh, acc[t][nt], 0, 0, 0);
                acc[t][nt] = __builtin_amdgcn_mfma_f32_16x16x32_f16(al[t], bh, acc[t][nt], 0, 0, 0);
                acc[t][nt] = __builtin_amdgcn_mfma_f32_16x16x32_f16(ah[t], bl, acc[t][nt], 0, 0, 0);
            }
        }
        // prefetch next tile's sub0
        {
            int itn = (it2 < 7) ? it2 + 1 : 7;
            int nb = (((itn >> 2) * 4) + (itn & 3)) * 1024 + wv * 256;
            rhA[0] = gh4[nb + lane]; rhA[1] = gh4[nb + 64 + lane];
            rlA[0] = gl4[nb + lane]; rlA[1] = gl4[nb + 64 + lane];
        }
        // write sub1 es
        #pragma unroll
        for (int q = 0; q < 2; ++q) {
            int a = (q * 16 + (lane >> 2)) * 40 + (lane & 3) * 8;
            *(uint4*)&esw_h[a] = rhB[q];
            *(uint4*)&esw_l[a] = rlB[q];
        }
        // ---- sub 1 MFMAs
        #pragma unroll
        for (int nt = 0; nt < 2; ++nt) {
            int a = (nt * 16 + l15) * 40 + quad * 8;
            half8 bh = *(const half8*)&esw_h[a];
            half8 bl = *(const half8*)&esw_l[a];
            #pragma unroll
            for (int t = 0; t < 4; ++t) {
                acc[t][2 + nt] = __builtin_amdgcn_mfma_f32_16x16x32_f16(ah[t], bh, acc[t][2 + nt], 0, 0, 0);
                acc[t][2 + nt] = __builtin_amdgcn_mfma_f32_16x16x32_f16(al[t], bh, acc[t][2 + nt], 0, 0, 0);
                acc[t][2 + nt] = __builtin_amdgcn_mfma_f32_16x16x32_f16(ah[t], bl, acc[t][2 + nt], 0, 0, 0);
            }
        }
        // fold at end of each nc (codes ascend across g and nc -> strict <)
        if ((it2 & 3) == 3) {
            int ncv = it2 >> 2;
            #pragma unroll
            for (int g = 0; g < 4; ++g) {
                int c = ncv * 256 + wv * 64 + g * 16 + l15;
                float ee = e2[c];
                #pragma unroll
                for (int t = 0; t < 4; ++t)
                    #pragma unroll
                    for (int r = 0; r < 4; ++r) {
                        float s = fmaf(-2.f, acc[t][g][r], ee);
                        if (s < bestD[t][r]) { bestD[t][r] = s; bestI[t][r] = c; }
                        acc[t][g][r] = 0.f;
                    }
            }
        }
    }

    // reduce across the 16 l15 lanes (different codes, same rows)
    #pragma unroll
    for (int mask = 1; mask <= 8; mask <<= 1) {
        #pragma unroll
        for (int t = 0; t < 4; ++t)
            #pragma unroll
            for (int r = 0; r < 4; ++r) {
                float od = __shfl_xor(bestD[t][r], mask, 64);
                int   oi = __shfl_xor(bestI[t][r], mask, 64);
                if (od < bestD[t][r] || (od == bestD[t][r] && oi < bestI[t][r])) {
                    bestD[t][r] = od; bestI[t][r] = oi;
                }
            }
    }

    // overlay scratch onto xs (dead after MFMA) -- barrier first
    __syncthreads();
    float* wbD  = (float*)smem;
    int*   wbI  = (int*)(smem + 1024);
    int*   bidx = (int*)(smem + 2048);
    float* wred = (float*)(smem + 2304);

    if (l15 == 0) {
        #pragma unroll
        for (int t = 0; t < 4; ++t)
            #pragma unroll
            for (int r = 0; r < 4; ++r) {
                int m = t * 16 + quad * 4 + r;   // C layout: row=(lane>>4)*4+reg
                wbD[wv * 64 + m] = bestD[t][r];
                wbI[wv * 64 + m] = bestI[t][r];
            }
    }
    __syncthreads();
    if (tid < 64) {
        float bd = wbD[tid]; int bi = wbI[tid];
        #pragma unroll
        for (int w = 1; w < 4; ++w) {
            float od = wbD[w * 64 + tid]; int oi = wbI[w * 64 + tid];
            if (od < bd || (od == bd && oi < bi)) { bd = od; bi = oi; }
        }
        bidx[tid] = bi;
        out[IDX_OFF + n0 + tid] = (float)bi;
    }
    __syncthreads();

    // epilogue: quantized output (exact fp32 gather) + loss partial
    float lsum = 0.f;
    #pragma unroll 4
    for (int r = 0; r < 32; ++r) {
        int lin = tid + r * 256;
        int d = lin >> 6, i = lin & 63;
        float q  = emb[d * K + bidx[i]];
        float zz = zb[d * HW + i];
        out[Q_OFF + b * ZSTRIDE_B + d * HW + hw0 + i] = q;
        float df = q - zz;
        lsum = fmaf(df, df, lsum);
    }
    #pragma unroll
    for (int m = 32; m >= 1; m >>= 1) lsum += __shfl_xor(lsum, m, 64);
    if ((tid & 63) == 0) wred[wv] = lsum;
    __syncthreads();
    if (tid == 0) {
        float t = wred[0] + wred[1] + wred[2] + wred[3];
        atomicAdd(lossAcc, t);
    }
}

// ---------------------------------------------------------------------------
#define DC 8
// k_ema3: LDS-privatized segment sums -> PARTIAL writes (no global atomics).
// 512 blocks = 32 batches x 16 d-chunks; block writes its DC*K partial block.
__global__ __launch_bounds__(256) void k_ema3(const float* __restrict__ z,
                                              const float* __restrict__ out,
                                              float* __restrict__ part,
                                              float* __restrict__ cntp) {
    __shared__ float acc[DC][K];
    __shared__ float cnt[K];

    const int tid = threadIdx.x;
    const int dchunk = blockIdx.x & 15;
    const int b      = blockIdx.x >> 4;
    const int d0 = dchunk * DC;
    const bool doCnt = (dchunk == 0);

    for (int i = tid; i < DC * K; i += 256) ((float*)acc)[i] = 0.f;
    if (doCnt) for (int i = tid; i < K; i += 256) cnt[i] = 0.f;
    __syncthreads();

    const float* zb  = z + b * ZSTRIDE_B;
    const float* idp = out + IDX_OFF + b * HW;
    for (int t = 0; t < HW; t += 1024) {
        const int p = t + 4 * tid;
        int k0 = (int)idp[p + 0];
        int k1 = (int)idp[p + 1];
        int k2 = (int)idp[p + 2];
        int k3 = (int)idp[p + 3];
        if (doCnt) {
            atomicAdd(&cnt[k0], 1.f); atomicAdd(&cnt[k1], 1.f);
            atomicAdd(&cnt[k2], 1.f); atomicAdd(&cnt[k3], 1.f);
        }
        #pragma unroll
        for (int d = 0; d < DC; ++d) {
            float4 zv = *(const float4*)(zb + (d0 + d) * HW + p);
            atomicAdd(&acc[d][k0], zv.x);
            atomicAdd(&acc[d][k1], zv.y);
            atomicAdd(&acc[d][k2], zv.z);
            atomicAdd(&acc[d][k3], zv.w);
        }
    }
    __syncthreads();

    float* pp = part + (size_t)blockIdx.x * (DC * K);
    for (int i = tid; i < DC * K / 4; i += 256)
        ((float4*)pp)[i] = ((const float4*)acc)[i];
    if (doCnt) for (int i = tid; i < K; i += 256) cntp[b * K + i] = cnt[i];
}

// k_emared: esum[d][k] = sum over 32 batch-partials (plain coalesced loads).
__global__ __launch_bounds__(256) void k_emared(const float* __restrict__ part,
                                                float* __restrict__ esum) {
    int id = blockIdx.x * 256 + threadIdx.x;   // 65536 cells
    int d = id >> 9, k = id & 511;
    int dchunk = d >> 3, dd = d & 7;
    const float* p = part + dchunk * (DC * K) + dd * K + k;
    float s = 0.f;
    #pragma unroll 8
    for (int b = 0; b < 32; ++b) s += p[(size_t)b * 16 * DC * K];
    esum[id] = s;
}

// ---------------------------------------------------------------------------
// k_ema2f: fallback (small ws) — atomic flush version.
__global__ __launch_bounds__(256) void k_ema2f(const float* __restrict__ z,
                                               const float* __restrict__ out,
                                               float* __restrict__ enc,
                                               float* __restrict__ esum) {
    __shared__ float acc[DC][K];
    __shared__ float cnt[K];
    const int tid = threadIdx.x;
    const int dchunk = blockIdx.x & 15;
    const int b      = blockIdx.x >> 4;
    const int d0 = dchunk * DC;
    const bool doCnt = (dchunk == 0);
    for (int i = tid; i < DC * K; i += 256) ((float*)acc)[i] = 0.f;
    if (doCnt) for (int i = tid; i < K; i += 256) cnt[i] = 0.f;
    __syncthreads();
    const float* zb  = z + b * ZSTRIDE_B;
    const float* idp = out + IDX_OFF + b * HW;
    for (int t = 0; t < HW; t += 1024) {
        const int p = t + 4 * tid;
        int k0 = (int)idp[p + 0], k1 = (int)idp[p + 1];
        int k2 = (int)idp[p + 2], k3 = (int)idp[p + 3];
        if (doCnt) {
            atomicAdd(&cnt[k0], 1.f); atomicAdd(&cnt[k1], 1.f);
            atomicAdd(&cnt[k2], 1.f); atomicAdd(&cnt[k3], 1.f);
        }
        #pragma unroll
        for (int d = 0; d < DC; ++d) {
            float4 zv = *(const float4*)(zb + (d0 + d) * HW + p);
            atomicAdd(&acc[d][k0], zv.x); atomicAdd(&acc[d][k1], zv.y);
            atomicAdd(&acc[d][k2], zv.z); atomicAdd(&acc[d][k3], zv.w);
        }
    }
    __syncthreads();
    for (int i = tid; i < DC * K; i += 256) {
        int d = i >> 9, k = i & 511;
        atomicAdd(&esum[(d0 + d) * K + k], acc[d][k]);
    }
    if (doCnt) for (int i = tid; i < K; i += 256) atomicAdd(&enc[i], cnt[i]);
}

// ---------------------------------------------------------------------------
__global__ __launch_bounds__(512) void k_final(const float* __restrict__ cntp,
                                               int nP,
                                               const float* __restrict__ esum,
                                               const float* __restrict__ cs_in,
                                               const float* __restrict__ eavg_in,
                                               const float* __restrict__ lossAcc,
                                               float* __restrict__ out) {
    __shared__ float red[512];
    int k = threadIdx.x;
    float e = 0.f;
    for (int p = 0; p < nP; ++p) e += cntp[p * 512 + k];
    float ncs = fmaf(cs_in[k], 0.99f, 0.01f * e);
    red[k] = ncs;
    __syncthreads();
    for (int s = 256; s > 0; s >>= 1) {
        if (k < s) red[k] += red[k + s];
        __syncthreads();
    }
    float nn = fmaxf(red[0], 1e-5f);
    float cs = (ncs + 1e-5f) / (nn + (float)K * 1e-5f) * nn;
    out[NCS_OFF + k] = ncs;
    if (k == 0) out[LOSS_OFF] = lossAcc[0] * 1.25f / 16777216.0f;
    float inv_cs = 1.0f / cs;
    #pragma unroll 4
    for (int d = 0; d < DIM; ++d) {
        float ea = fmaf(eavg_in[d * K + k], 0.99f, 0.01f * esum[d * K + k]);
        out[NEA_OFF + d * K + k] = ea;
        out[NEMB_OFF + d * K + k] = ea * inv_cs;
    }
}

// ---------------------------------------------------------------------------
extern "C" void kernel_launch(void* const* d_in, const int* in_sizes, int n_in,
                              void* d_out, int out_size, void* d_ws, size_t ws_size,
                              hipStream_t stream) {
    const float* z     = (const float*)d_in[0];
    const float* emb   = (const float*)d_in[1];
    const float* cs_in = (const float*)d_in[2];
    const float* eavg  = (const float*)d_in[3];
    float* out = (float*)d_out;
    float* wsF = (float*)d_ws;

    const size_t needP = (size_t)(82944 + 2097152) * 4;   // ~8.72 MB

    if (ws_size >= needP) {
        // partial-sum path (no global atomics in EMA)
        float* e2   = wsF + 0;
        float* loss = wsF + 512;
        float* cnt  = wsF + 1024;                 // 32 x 512
        u16*   ehi  = (u16*)(wsF + 17408);        // 65536 f16
        u16*   elo  = (u16*)(wsF + 50176);
        float* esum = wsF + 17408;                // reuses ehi/elo region after k_assign
        float* part = wsF + 82944;                // 512 x 4096 floats (8 MB)

        hipMemsetAsync(loss, 0, sizeof(float), stream);
        k_prep<<<256, 256, 0, stream>>>(emb, ehi, elo);
        k_e2<<<1, 512, 0, stream>>>(emb, e2);
        k_assign<<<NPOS / 64, 256, 0, stream>>>(z, emb, (const uint4*)ehi,
                                                (const uint4*)elo, e2, out, loss);
        k_ema3<<<512, 256, 0, stream>>>(z, out, part, cnt);
        k_emared<<<256, 256, 0, stream>>>(part, esum);
        k_final<<<1, 512, 0, stream>>>(cnt, 32, esum, cs_in, eavg, loss, out);
    } else {
        // fallback: atomic-flush path (fits in ~270 KB of ws)
        float* e2   = wsF + 0;
        float* loss = wsF + 512;
        float* enc  = wsF + 1024;
        u16*   ehi  = (u16*)(wsF + 2048);         // overlays esum
        u16*   elo  = (u16*)(wsF + 34816);
        float* esum = wsF + 2048;

        hipMemsetAsync(wsF + 512, 0, 1024 * sizeof(float), stream);  // loss + enc
        k_prep<<<256, 256, 0, stream>>>(emb, ehi, elo);
        k_e2<<<1, 512, 0, stream>>>(emb, e2);
        k_assign<<<NPOS / 64, 256, 0, stream>>>(z, emb, (const uint4*)ehi,
                                                (const uint4*)elo, e2, out, loss);
        hipMemsetAsync(esum, 0, 65536 * sizeof(float), stream);
        k_ema2f<<<512, 256, 0, stream>>>(z, out, enc, esum);
        k_final<<<1, 512, 0, stream>>>(enc, 1, esum, cs_in, eavg, loss, out);
    }
}